// Round 9
// baseline (514.493 us; speedup 1.0000x reference)
//
#include <hip/hip_runtime.h>
#include <cmath>
#include <complex>
#include <cstring>
#include <vector>

#ifndef M_PI
#define M_PI 3.14159265358979323846
#endif

// ======================================================================
// Host-side Wigner-D constant generation (double precision, e3nn conv.)
// Runs once at dlopen (static constructor) — outside graph capture.
// ======================================================================
namespace wig {

using cplx = std::complex<double>;

static void matmul(const double* A, const double* B, double* C, int d) {
    for (int i = 0; i < d; ++i)
        for (int j = 0; j < d; ++j) {
            double s = 0;
            for (int k = 0; k < d; ++k) s += A[i*d+k]*B[k*d+j];
            C[i*d+j] = s;
        }
}

struct Gen { std::vector<double> X0, X1; int d; };

static Gen make_gen(int l) {
    int d = 2*l+1;
    std::vector<cplx> rais(d*d, cplx(0,0)), low(d*d, cplx(0,0));
    for (int i = 0; i+1 < d; ++i) {
        double m = -l + i;
        rais[(i+1)*d + i] = cplx(-std::sqrt(l*(l+1.0) - m*(m+1.0)), 0.0);
    }
    for (int i = 0; i+1 < d; ++i) {
        double m = -l + 1 + i;
        low[i*d + (i+1)] = cplx(std::sqrt(l*(l+1.0) - m*(m-1.0)), 0.0);
    }
    std::vector<cplx> Xc0(d*d, cplx(0,0)), Xc1(d*d, cplx(0,0));
    for (int i = 0; i < d*d; ++i) Xc0[i] = 0.5*(rais[i] + low[i]);
    for (int i = 0; i < d; ++i) Xc1[i*d+i] = cplx(0.0, (double)(-l + i));
    std::vector<cplx> q(d*d, cplx(0,0));
    double is2 = 1.0/std::sqrt(2.0);
    for (int m = -l; m < 0; ++m) {
        q[(l+m)*d + (l-m)] = cplx(is2, 0);
        q[(l+m)*d + (l+m)] = cplx(0, -is2);
    }
    q[l*d + l] = cplx(1,0);
    for (int m = 1; m <= l; ++m) {
        double sgn = (m & 1) ? -1.0 : 1.0;
        q[(l+m)*d + (l+m)] = cplx(sgn*is2, 0);
        q[(l+m)*d + (l-m)] = cplx(0, sgn*is2);
    }
    cplx f;
    switch (l & 3) { case 0: f = cplx(1,0); break; case 1: f = cplx(0,-1); break;
                     case 2: f = cplx(-1,0); break; default: f = cplx(0,1); break; }
    for (auto& v : q) v *= f;
    Gen g; g.d = d; g.X0.assign(d*d, 0.0); g.X1.assign(d*d, 0.0);
    const std::vector<cplx>* Xs[2] = {&Xc0, &Xc1};
    std::vector<double>* Xr[2] = {&g.X0, &g.X1};
    for (int a = 0; a < 2; ++a) {
        std::vector<cplx> t1(d*d, cplx(0,0)), t2(d*d, cplx(0,0));
        for (int i = 0; i < d; ++i)
            for (int k = 0; k < d; ++k) {
                cplx x = (*Xs[a])[i*d+k];
                if (x == cplx(0,0)) continue;
                for (int j = 0; j < d; ++j) t1[i*d+j] += x*q[k*d+j];
            }
        for (int k = 0; k < d; ++k)
            for (int i = 0; i < d; ++i) {
                cplx qc = std::conj(q[k*d+i]);
                if (qc == cplx(0,0)) continue;
                for (int j = 0; j < d; ++j) t2[i*d+j] += qc*t1[k*d+j];
            }
        for (int i = 0; i < d*d; ++i) (*Xr[a])[i] = t2[i].real();
    }
    return g;
}

static std::vector<double> expm_t(const std::vector<double>& A, int d, double t) {
    std::vector<double> M(d*d);
    for (int i = 0; i < d*d; ++i) M[i] = A[i]*t;
    double nrm = 0;
    for (int i = 0; i < d; ++i) {
        double rs = 0;
        for (int j = 0; j < d; ++j) rs += std::fabs(M[i*d+j]);
        if (rs > nrm) nrm = rs;
    }
    int sq = 0;
    while (nrm > 0.5) { nrm *= 0.5; ++sq; }
    double sc = std::ldexp(1.0, -sq);
    for (auto& v : M) v *= sc;
    std::vector<double> R(d*d, 0.0), T(d*d, 0.0), tmp(d*d);
    for (int i = 0; i < d; ++i) { R[i*d+i] = 1.0; T[i*d+i] = 1.0; }
    for (int k = 1; k <= 26; ++k) {
        matmul(T.data(), M.data(), tmp.data(), d);
        double inv = 1.0/(double)k;
        for (int i = 0; i < d*d; ++i) { T[i] = tmp[i]*inv; R[i] += T[i]; }
    }
    for (int s = 0; s < sq; ++s) { matmul(R.data(), R.data(), tmp.data(), d); R = tmp; }
    return R;
}

static std::vector<double> wigD(const Gen& g, double a, double b, double c) {
    auto Ea = expm_t(g.X1, g.d, a);
    auto Eb = expm_t(g.X0, g.d, b);
    auto Ec = expm_t(g.X1, g.d, c);
    std::vector<double> t(g.d*g.d), r(g.d*g.d);
    matmul(Ea.data(), Eb.data(), t.data(), g.d);
    matmul(t.data(), Ec.data(), r.data(), g.d);
    return r;
}

} // namespace wig

// ======================================================================
// bf16 helpers (hi/lo split), host + device
// ======================================================================
static inline unsigned short f2bf_h(float f) {
    unsigned u; std::memcpy(&u, &f, 4);
    unsigned r = (u + 0x7FFFu + ((u >> 16) & 1u)) >> 16;
    return (unsigned short)r;
}
static inline float bf2f_h(unsigned short s) {
    unsigned u = ((unsigned)s) << 16; float f; std::memcpy(&f, &u, 4); return f;
}
__device__ __forceinline__ unsigned short f2bf_d(float f) {
    unsigned u = __float_as_uint(f);
    return (unsigned short)((u + 0x7FFFu + ((u >> 16) & 1u)) >> 16);
}
__device__ __forceinline__ float bf2f_d(unsigned short s) {
    return __uint_as_float(((unsigned)s) << 16);
}

typedef short short8 __attribute__((ext_vector_type(8)));
typedef float f32x4 __attribute__((ext_vector_type(4)));

#define GLOAD_LDS16(g, l) \
    __builtin_amdgcn_global_load_lds( \
        (const __attribute__((address_space(1))) unsigned int*)(g), \
        (__attribute__((address_space(3))) unsigned int*)(l), 16, 0, 0)

// ======================================================================
// Globals: device constants + private scratch (allocated at dlopen)
// ======================================================================
static float*          g_QW   = nullptr;  // [4096]
static float*          g_YS2  = nullptr;  // [24*9]
static unsigned short* g_DKS  = nullptr;  // [192 rows i][576] = [Dh|Dl|Dh] of D_K^T
static unsigned short* g_B1   = nullptr;  // [4096][576]  = [Dh|Dl|Dh] per row (act GEMM1 B)
static unsigned short* g_B2T  = nullptr;  // [192][8192] = [Dh|Dl] columns (act GEMM2 B)
static float*          g_scratch = nullptr;

// scratch layout (float units, all 16B-aligned)
static const size_t WS_OFF   = 0;                       // Wsplit 8192*576 ush = 2359296 fl
static const size_t AP_OFF   = WS_OFF + 2359296;        // lin Apack 2027520 ush = 1013760 fl
static const size_t BP_OFF   = AP_OFF + 1013760;        // lin Bpack 4055040 ush = 2027520 fl
static const size_t A1_OFF   = BP_OFF + 2027520;        // A1 8192*576 ush = 2359296 fl
static const size_t GH_OFF   = A1_OFF + 2359296;        // 8192*4096 ush = 16777216 fl
static const size_t GL_OFF   = GH_OFF + 16777216;
static const size_t PP_OFF   = GL_OFF + 16777216;       // KC*M*192 fl (max 12582912)
static const size_t ZB_OFF   = PP_OFF + 12582912;       // 8192*192 fl
static const size_t PSI2_OFF = ZB_OFF + 1572864;        // 147456 fl
static const size_t TOTAL_F  = PSI2_OFF + 147456;

namespace {
struct InitCtx {
    InitCtx() {
        using namespace wig;
        Gen gens[5];
        for (int l = 0; l <= 4; ++l) gens[l] = make_gen(l);
        const int loff[5] = {0, 1, 10, 35, 84};

        // ---- near-identity SO3 grid / D_K [192 x 165] ----
        double alpha8[8], beta3[3], preg8[8];
        for (int i = 0; i < 8; ++i) alpha8[i] = 2.0*M_PI*i/8.0;
        for (int i = 0; i < 3; ++i) beta3[i] = (i+1)*(M_PI/8.0)/3.0;
        for (int i = 0; i < 8; ++i) preg8[i] = -2.0*M_PI + i*(4.0*M_PI/7.0);
        std::vector<float> hDK((size_t)192*165);
        for (int ia = 0; ia < 8; ++ia)
        for (int ib = 0; ib < 3; ++ib)
        for (int ic = 0; ic < 8; ++ic) {
            int n = ia*24 + ib*8 + ic;
            double a = alpha8[ia], b = beta3[ib], c = preg8[ic] - alpha8[ia];
            for (int l = 0; l <= 4; ++l) {
                int d = 2*l+1;
                auto Dl = wigD(gens[l], a, b, c);
                double s = std::sqrt(2.0*l+1.0);
                for (int e = 0; e < d*d; ++e)
                    hDK[(size_t)n*165 + loff[l] + e] = (float)(s*Dl[e]);
            }
        }

        // ---- full SO3 grid / D_ACT [4096 x 165], QW [4096] ----
        double ag[16], bg[16];
        for (int i = 0; i < 16; ++i) ag[i] = 2.0*M_PI*i/16.0;
        for (int i = 0; i < 16; ++i) bg[i] = (i+0.5)*M_PI/16.0;
        std::vector<std::vector<double>> Ea[5], Eb[5];
        for (int l = 0; l <= 4; ++l) {
            Ea[l].resize(16); Eb[l].resize(16);
            for (int i = 0; i < 16; ++i) {
                Ea[l][i] = expm_t(gens[l].X1, gens[l].d, ag[i]);
                Eb[l][i] = expm_t(gens[l].X0, gens[l].d, bg[i]);
            }
        }
        double qsum = 0;
        for (int ib = 0; ib < 16; ++ib) qsum += std::sin(bg[ib]);
        qsum *= 256.0;
        std::vector<float> hDA((size_t)4096*165), hQW(4096);
        for (int ia = 0; ia < 16; ++ia)
        for (int ib = 0; ib < 16; ++ib) {
            for (int ic = 0; ic < 16; ++ic)
                hQW[ia*256 + ib*16 + ic] = (float)(std::sin(bg[ib]) / qsum);
            for (int l = 0; l <= 4; ++l) {
                int d = gens[l].d;
                std::vector<double> tAB((size_t)d*d), r((size_t)d*d);
                matmul(Ea[l][ia].data(), Eb[l][ib].data(), tAB.data(), d);
                double s = std::sqrt(2.0*l+1.0);
                for (int ic = 0; ic < 16; ++ic) {
                    int n = ia*256 + ib*16 + ic;
                    matmul(tAB.data(), Ea[l][ic].data(), r.data(), d);
                    for (int e = 0; e < d*d; ++e)
                        hDA[(size_t)n*165 + loff[l] + e] = (float)(s*r[e]);
                }
            }
        }

        // ---- S2 grid / Y_S2 [24 x 9] ----
        const int l2off[3] = {0, 1, 4};
        std::vector<float> hY((size_t)24*9);
        for (int ia = 0; ia < 8; ++ia)
        for (int ib = 0; ib < 3; ++ib) {
            int n = ia*3 + ib;
            for (int l = 0; l <= 2; ++l) {
                int d = 2*l+1;
                auto Dl = wigD(gens[l], alpha8[ia], beta3[ib], 0.0);
                double s = std::sqrt(2.0*l+1.0);
                for (int u = 0; u < d; ++u)
                    hY[(size_t)n*9 + l2off[l] + u] = (float)(s*Dl[u*d + l]);
            }
        }

        // ---- D_K^T split for psi MFMA GEMM: [192 rows i][576] = [Dh|Dl|Dh] ----
        std::vector<unsigned short> hDKS((size_t)192*576, 0);
        for (int i = 0; i < 165; ++i)
            for (int k = 0; k < 192; ++k) {
                float f = hDK[(size_t)k*165 + i];
                unsigned short h = f2bf_h(f);
                unsigned short lo = f2bf_h(f - bf2f_h(h));
                hDKS[(size_t)i*576 + k]       = h;
                hDKS[(size_t)i*576 + 192 + k] = lo;
                hDKS[(size_t)i*576 + 384 + k] = h;
            }

        // ---- hi/lo split of D_ACT, padded 165 -> 192 ----
        std::vector<unsigned short> Dh((size_t)4096*192, 0), Dl2((size_t)4096*192, 0);
        for (int n = 0; n < 4096; ++n)
            for (int i = 0; i < 165; ++i) {
                float f = hDA[(size_t)n*165 + i];
                unsigned short h = f2bf_h(f);
                Dh[(size_t)n*192 + i] = h;
                Dl2[(size_t)n*192 + i] = f2bf_h(f - bf2f_h(h));
            }
        std::vector<unsigned short> hB1((size_t)4096*576);
        for (int n = 0; n < 4096; ++n)
            for (int j = 0; j < 192; ++j) {
                hB1[(size_t)n*576 + j]       = Dh[(size_t)n*192 + j];
                hB1[(size_t)n*576 + 192 + j] = Dl2[(size_t)n*192 + j];
                hB1[(size_t)n*576 + 384 + j] = Dh[(size_t)n*192 + j];
            }
        // B2T [192][8192]: [Dh | Dl] (Gh.Dh + Gh.Dl + Gl.Dh handled in-kernel)
        std::vector<unsigned short> hB2T((size_t)192*8192);
        for (int j = 0; j < 192; ++j)
            for (int k = 0; k < 4096; ++k) {
                hB2T[(size_t)j*8192 + k]        = Dh[(size_t)k*192 + j];
                hB2T[(size_t)j*8192 + 4096 + k] = Dl2[(size_t)k*192 + j];
            }

        // ---- upload ----
        (void)hipMalloc((void**)&g_QW,  hQW.size()*sizeof(float));
        (void)hipMalloc((void**)&g_YS2, hY.size()*sizeof(float));
        (void)hipMalloc((void**)&g_DKS, hDKS.size()*sizeof(unsigned short));
        (void)hipMalloc((void**)&g_B1,  hB1.size()*sizeof(unsigned short));
        (void)hipMalloc((void**)&g_B2T, hB2T.size()*sizeof(unsigned short));
        (void)hipMalloc((void**)&g_scratch, TOTAL_F*sizeof(float));
        (void)hipMemcpy(g_QW,  hQW.data(),  hQW.size()*sizeof(float),  hipMemcpyHostToDevice);
        (void)hipMemcpy(g_YS2, hY.data(),   hY.size()*sizeof(float),   hipMemcpyHostToDevice);
        (void)hipMemcpy(g_DKS, hDKS.data(), hDKS.size()*sizeof(unsigned short), hipMemcpyHostToDevice);
        (void)hipMemcpy(g_B1,  hB1.data(),  hB1.size()*sizeof(unsigned short),  hipMemcpyHostToDevice);
        (void)hipMemcpy(g_B2T, hB2T.data(), hB2T.size()*sizeof(unsigned short), hipMemcpyHostToDevice);
    }
};
static InitCtx g_init_ctx;
} // namespace

// ======================================================================
// Arg structs (passed by value)
// ======================================================================
struct PsiArgs {
    const unsigned short* A;   // Wsplit [M][576]
    const unsigned short* B;   // DKsplit [192][576]
    unsigned short* O;         // lin Bpack
    int boff[5], kp[5];
    int fout;
};
struct APackArgs {
    const float* X;
    unsigned short* O;         // lin Apack
    int cum[6];
    int aoff[5], kp[5], kl[5];
    int bs, fs, total;
};
struct LinArgs {
    const unsigned short* A;   // Apack
    const unsigned short* B;   // Bpack
    unsigned short* O;         // A1 [P][576]
    int cum[6];
    int aoff[5], boff[5], kp[5];
    float rs[5];
    int fout;
};

__device__ __constant__ int c_loff[5] = {0, 1, 10, 35, 84};

// Bank-conflict swizzle (T2, both-sides involution with linear global_load_lds):
//  - staging chunk c (16B units): fetch global col16 = (c ^ (c>>3)) & 7
//  - read of (row, col16): LDS col16' = col16 ^ (row & 7)
__device__ __forceinline__ int swz_src8(int c) { return ((c ^ (c >> 3)) & 7) * 8; }

// ======================================================================
// Small kernels
// ======================================================================

// psi2 head: one thread per (x,y); psi2[x,y,i] = sum_k wl[x,y,k]*Y[k,i]/24
__global__ __launch_bounds__(256) void sph_psi2_kernel(
        const float* __restrict__ wl, const float* __restrict__ Y,
        float* __restrict__ psi2) {
    __shared__ float Ys[216];
    int tid = threadIdx.x;
    if (tid < 216) Ys[tid] = Y[tid];
    __syncthreads();
    int o = blockIdx.x*256 + tid;   // 16384 = 128*128
    const float* w = wl + (size_t)o*24;
    float wv[24];
    #pragma unroll
    for (int k = 0; k < 24; k += 4) {
        f32x4 v = *(const f32x4*)&w[k];
        wv[k] = v[0]; wv[k+1] = v[1]; wv[k+2] = v[2]; wv[k+3] = v[3];
    }
    float acc[9] = {};
    #pragma unroll
    for (int k = 0; k < 24; ++k)
        #pragma unroll
        for (int i = 0; i < 9; ++i)
            acc[i] += wv[k] * Ys[k*9 + i];
    float* po = psi2 + (size_t)o*9;
    #pragma unroll
    for (int i = 0; i < 9; ++i) po[i] = acc[i] * (1.0f/24.0f);
}

// s2 head: one wave per (b,y). out[b,y,idx9], K-reduce over x (128) via lanes.
__global__ __launch_bounds__(64) void sph_s2_wave(
        const float* __restrict__ z, const float* __restrict__ psi2,
        float* __restrict__ out) {
    int blk = blockIdx.x;          // 8192 = 64*128
    int b = blk >> 7, y = blk & 127;
    int lane = threadIdx.x;
    float acc[9] = {};
    #pragma unroll
    for (int xi = 0; xi < 2; ++xi) {
        int x = lane + xi*64;
        const float* zr = z + (size_t)(b*128 + x)*192;
        const float* pr = psi2 + (size_t)(x*128 + y)*9;
        float p[9];
        #pragma unroll
        for (int i = 0; i < 9; ++i) p[i] = pr[i];
        acc[0] += p[0] * zr[0];
        #pragma unroll
        for (int u = 0; u < 3; ++u)
            #pragma unroll
            for (int m = 0; m < 3; ++m)
                acc[1+m] += p[1+u] * zr[1 + u*3 + m];
        #pragma unroll
        for (int u = 0; u < 5; ++u)
            #pragma unroll
            for (int m = 0; m < 5; ++m)
                acc[4+m] += p[4+u] * zr[10 + u*5 + m];
    }
    #pragma unroll
    for (int i = 0; i < 9; ++i) {
        float v = acc[i];
        #pragma unroll
        for (int off = 32; off > 0; off >>= 1)
            v += __shfl_down(v, off, 64);
        acc[i] = v;
    }
    if (lane == 0) {
        float* po = out + (size_t)blk*9;
        const float s0 = 0.0883883476483184406f;   // 1/sqrt(128)
        const float s1 = 0.0510310363079828938f;   // 1/sqrt(384)
        const float s2 = 0.0395284707521047416f;   // 1/sqrt(640)
        po[0] = acc[0] * s0;
        po[1] = acc[1] * s1; po[2] = acc[2] * s1; po[3] = acc[3] * s1;
        po[4] = acc[4] * s2; po[5] = acc[5] * s2; po[6] = acc[6] * s2;
        po[7] = acc[7] * s2; po[8] = acc[8] * s2;
    }
}

// w [M][192] fp32 -> Wsplit [M][576] = [Wh|Wh|Wl]
__global__ void sph_wpack_kernel(const float* __restrict__ w, unsigned short* __restrict__ o, int total) {
    int t = blockIdx.x*blockDim.x + threadIdx.x;
    if (t >= total) return;
    int row = t / 192, k = t % 192;
    float v = w[t];
    unsigned short hi = f2bf_d(v);
    unsigned short lo = f2bf_d(v - bf2f_d(hi));
    size_t b = (size_t)row*576 + k;
    o[b] = hi; o[b+192] = hi; o[b+384] = lo;
}

// lin A-pack: X (fp32, block-l layout) -> Apack bf16 [Ah|Ah|Al] per l
__global__ void sph_apack_kernel(APackArgs ar) {
    int t = blockIdx.x*blockDim.x + threadIdx.x;
    if (t >= ar.total) return;
    int l = 0;
    #pragma unroll
    for (int i = 1; i < 5; ++i) if (t >= ar.cum[i]) l = i;
    int e = t - ar.cum[l];
    int d = 2*l + 1;
    int K = ar.kl[l];
    int row = e / K, k = e % K;
    int b = row / d, m = row % d;
    int x = k / d, u = k % d;
    float v = ar.X[(size_t)b*ar.bs + (size_t)x*ar.fs + c_loff[l] + u*d + m];
    unsigned short hi = f2bf_d(v);
    unsigned short lo = f2bf_d(v - bf2f_d(hi));
    int kp = ar.kp[l];
    size_t base = (size_t)ar.aoff[l] + (size_t)row*(3*kp);
    ar.O[base + k] = hi; ar.O[base + kp + k] = hi; ar.O[base + 2*kp + k] = lo;
}

// reduce split-K partials: z[p][j] = sum_{zz<KC} Pp[zz][p][j]
__global__ void sph_reduce_kernel(const float* __restrict__ Pp, float* __restrict__ z, int P, int KC) {
    int o = blockIdx.x*blockDim.x + threadIdx.x;
    if (o >= P*192) return;
    float s = 0.f;
    for (int zz = 0; zz < KC; ++zz) s += Pp[(size_t)zz*P*192 + o];
    z[o] = s;
}

// ======================================================================
// psi MFMA GEMM: P[(x,y),i] = (Wsplit . DKsplit^T)/192, epilogue scatters
// into lin Bpack bf16 [Bh|Bl|Bh]. Tile 64x64, 4 waves (row-split), K=576.
// ======================================================================
__global__ __launch_bounds__(256) void sph_psi_mfma(PsiArgs ar, int M) {
    __shared__ __align__(16) unsigned short As[64*64];
    __shared__ __align__(16) unsigned short Bs[64*64];
    int tid = threadIdx.x, lane = tid & 63, wid = tid >> 6;
    int l15 = lane & 15, l4 = lane >> 4;
    int sw = l15 & 7;
    int bm = blockIdx.x * 64, bn = blockIdx.y * 64;
    f32x4 acc[4] = {};
    for (int k0 = 0; k0 < 576; k0 += 64) {
        #pragma unroll
        for (int i = 0; i < 2; ++i) {
            int c = tid + i*256;
            int row = c >> 3, kb = swz_src8(c);
            GLOAD_LDS16(ar.A + (size_t)(bm + row)*576 + k0 + kb, As + c*8);
            GLOAD_LDS16(ar.B + (size_t)(bn + row)*576 + k0 + kb, Bs + c*8);
        }
        __syncthreads();
        #pragma unroll
        for (int ks = 0; ks < 2; ++ks) {
            int cs = ((ks*4 + l4) ^ sw) * 8;
            short8 av = *(const short8*)&As[(wid*16 + l15)*64 + cs];
            #pragma unroll
            for (int nj = 0; nj < 4; ++nj) {
                short8 bv = *(const short8*)&Bs[(nj*16 + l15)*64 + cs];
                acc[nj] = __builtin_amdgcn_mfma_f32_16x16x32_bf16(av, bv, acc[nj], 0, 0, 0);
            }
        }
        __syncthreads();
    }
    #pragma unroll
    for (int nj = 0; nj < 4; ++nj) {
        int i = bn + nj*16 + l15;
        if (i >= 165) continue;
        int l, st;
        if (i < 1)       { l = 0; st = 0;  }
        else if (i < 10) { l = 1; st = 1;  }
        else if (i < 35) { l = 2; st = 10; }
        else if (i < 84) { l = 3; st = 35; }
        else             { l = 4; st = 84; }
        int d = 2*l + 1;
        int w = i - st;
        int u = w / d, v = w % d;
        int kp = ar.kp[l];
        #pragma unroll
        for (int r = 0; r < 4; ++r) {
            int R = bm + wid*16 + l4*4 + r;
            int x = R / ar.fout, y = R % ar.fout;
            float val = acc[nj][r] * (1.0f/192.0f);
            unsigned short hi = f2bf_d(val);
            unsigned short lo = f2bf_d(val - bf2f_d(hi));
            size_t base = (size_t)ar.boff[l] + (size_t)(y*d + v)*(3*kp) + (x*d + u);
            ar.O[base] = hi; ar.O[base + kp] = lo; ar.O[base + 2*kp] = hi;
        }
    }
}

// ======================================================================
// lin MFMA GEMM: per-l O[(b,m),(y,v)] = A_l . B_l^T, epilogue writes A1
// [P][576] = [Yh|Yh|Yl] with scale 1/sqrt(Fin*d). Tile 64x64, 4 waves.
// ======================================================================
__global__ __launch_bounds__(256) void sph_lin_mfma(LinArgs ar) {
    int bid = blockIdx.x;
    int l = 0;
    #pragma unroll
    for (int i = 1; i < 5; ++i) if (bid >= ar.cum[i]) l = i;
    int t = bid - ar.cum[l];
    int d = 2*l + 1;
    int NB = (ar.fout >> 6) * d;
    int tm = t / NB, tn = t % NB;
    int K3 = 3 * ar.kp[l];
    const unsigned short* Ab = ar.A + ar.aoff[l] + (size_t)tm*64*K3;
    const unsigned short* Bb = ar.B + ar.boff[l] + (size_t)tn*64*K3;
    __shared__ __align__(16) unsigned short As[64*64];
    __shared__ __align__(16) unsigned short Bs[64*64];
    int tid = threadIdx.x, lane = tid & 63, wid = tid >> 6;
    int l15 = lane & 15, l4 = lane >> 4;
    int sw = l15 & 7;
    f32x4 acc[4] = {};
    for (int k0 = 0; k0 < K3; k0 += 64) {
        #pragma unroll
        for (int i = 0; i < 2; ++i) {
            int c = tid + i*256;
            int row = c >> 3, kb = swz_src8(c);
            GLOAD_LDS16(Ab + (size_t)row*K3 + k0 + kb, As + c*8);
            GLOAD_LDS16(Bb + (size_t)row*K3 + k0 + kb, Bs + c*8);
        }
        __syncthreads();
        #pragma unroll
        for (int ks = 0; ks < 2; ++ks) {
            int cs = ((ks*4 + l4) ^ sw) * 8;
            short8 av = *(const short8*)&As[(wid*16 + l15)*64 + cs];
            #pragma unroll
            for (int nj = 0; nj < 4; ++nj) {
                short8 bv = *(const short8*)&Bs[(nj*16 + l15)*64 + cs];
                acc[nj] = __builtin_amdgcn_mfma_f32_16x16x32_bf16(av, bv, acc[nj], 0, 0, 0);
            }
        }
        __syncthreads();
    }
    float rs = ar.rs[l];
    #pragma unroll
    for (int nj = 0; nj < 4; ++nj) {
        int col = tn*64 + nj*16 + l15;
        int y = col / d, v = col % d;
        #pragma unroll
        for (int r = 0; r < 4; ++r) {
            int row = tm*64 + wid*16 + l4*4 + r;
            int b = row / d, m = row % d;
            float val = acc[nj][r] * rs;
            unsigned short hi = f2bf_d(val);
            unsigned short lo = f2bf_d(val - bf2f_d(hi));
            size_t p = (size_t)(b*ar.fout + y)*576 + c_loff[l] + v*d + m;
            ar.O[p] = hi; ar.O[p + 192] = hi; ar.O[p + 384] = lo;
        }
    }
}

// ======================================================================
// MFMA GEMM 1: S = A1[M,576] . B1[4096,576]^T, epilogue g = sqrt2*relu(s)*qw[n],
// writes Gh/Gl bf16 [M][4096]. Tile 128x128, 4 waves (2x2), 16x16x32 bf16.
// Store path: acc -> LDS repack (16B-granule XOR swizzle) -> coalesced
// dwordx4 global stores (two passes: hi then lo).
// ======================================================================
__global__ __launch_bounds__(256) void sph_gemm1_mfma(
        const unsigned short* __restrict__ A, const unsigned short* __restrict__ B,
        const float* __restrict__ qw,
        unsigned short* __restrict__ Gh, unsigned short* __restrict__ Gl, int M) {
    constexpr int K = 576;
    __shared__ __align__(16) unsigned short Sh[128*128];   // 32 KB union
    unsigned short* As = Sh;              // [128*64]
    unsigned short* Bs = Sh + 128*64;     // [128*64]
    int tid = threadIdx.x;
    int lane = tid & 63, wid = tid >> 6;
    int wm = wid >> 1, wn = wid & 1;
    int bm = blockIdx.x * 128, bn = blockIdx.y * 128;
    int l15 = lane & 15, l4 = lane >> 4;
    int sw = l15 & 7;
    f32x4 acc[4][4] = {};
    for (int k0 = 0; k0 < K; k0 += 64) {
        #pragma unroll
        for (int i = 0; i < 4; ++i) {
            int c = tid + i*256;
            int row = c >> 3, kb = swz_src8(c);
            GLOAD_LDS16(A + (size_t)(bm + row)*K + k0 + kb, As + c*8);
            GLOAD_LDS16(B + (size_t)(bn + row)*K + k0 + kb, Bs + c*8);
        }
        __syncthreads();
        #pragma unroll
        for (int ks = 0; ks < 2; ++ks) {
            int cs = ((ks*4 + l4) ^ sw) * 8;
            short8 av[4], bv[4];
            #pragma unroll
            for (int mi = 0; mi < 4; ++mi)
                av[mi] = *(const short8*)&As[(wm*64 + mi*16 + l15)*64 + cs];
            #pragma unroll
            for (int nj = 0; nj < 4; ++nj)
                bv[nj] = *(const short8*)&Bs[(wn*64 + nj*16 + l15)*64 + cs];
            #pragma unroll
            for (int mi = 0; mi < 4; ++mi)
                #pragma unroll
                for (int nj = 0; nj < 4; ++nj)
                    acc[mi][nj] = __builtin_amdgcn_mfma_f32_16x16x32_bf16(av[mi], bv[nj], acc[mi][nj], 0, 0, 0);
        }
        __syncthreads();
    }
    // ---- epilogue: g = sqrt2*relu(s)*qw in-place ----
    const float SQ2 = 1.41421356237309515f;
    #pragma unroll
    for (int nj = 0; nj < 4; ++nj) {
        float q = qw[bn + wn*64 + nj*16 + l15] * SQ2;
        #pragma unroll
        for (int mi = 0; mi < 4; ++mi)
            #pragma unroll
            for (int r = 0; r < 4; ++r)
                acc[mi][nj][r] = fmaxf(acc[mi][nj][r], 0.f) * q;
    }
    // ---- two passes: 0 = hi -> Gh, 1 = lo -> Gl ----
    #pragma unroll
    for (int bpass = 0; bpass < 2; ++bpass) {
        unsigned short* Dst = bpass ? Gl : Gh;
        // write phase: fragment values into Sh[row][col^] (16B-granule swizzle)
        #pragma unroll
        for (int mi = 0; mi < 4; ++mi) {
            #pragma unroll
            for (int nj = 0; nj < 4; ++nj) {
                int col = wn*64 + nj*16 + l15;
                #pragma unroll
                for (int r = 0; r < 4; ++r) {
                    int row = wm*64 + mi*16 + l4*4 + r;
                    float g = acc[mi][nj][r];
                    unsigned short hi = f2bf_d(g);
                    unsigned short val = bpass ? f2bf_d(g - bf2f_d(hi)) : hi;
                    int scol = (((col >> 3) ^ (row & 7)) << 3) | (col & 7);
                    Sh[row*128 + scol] = val;
                }
            }
        }
        __syncthreads();
        // store phase: contiguous 16B reads + coalesced dwordx4 stores
        int srow = tid >> 4, scg = tid & 15;
        #pragma unroll
        for (int rr = 0; rr < 8; ++rr) {
            int row = rr*16 + srow;
            int cg = scg ^ (row & 7);
            f32x4 v = *(const f32x4*)&Sh[row*128 + cg*8];
            *(f32x4*)&Dst[(size_t)(bm + row)*4096 + bn + scg*8] = v;
        }
        __syncthreads();
    }
}

// ======================================================================
// MFMA GEMM 2 (full-N tile): Z[M,192] = Gh.Dh + Gh.Dl + Gl.Dh over phys K=4096,
// split into KC chunks (blockIdx.y). Tile 128 rows x 192 cols, 4 waves
// (wave tile 32x192). Stages Gh/Gl (16KB ea) + Dh/Dl slabs (24KB ea) = 80KB LDS.
// Partials fp32 -> Pp[zc][M][192].
// ======================================================================
__global__ __launch_bounds__(256) void sph_gemm2_mfma(
        const unsigned short* __restrict__ Gh, const unsigned short* __restrict__ Gl,
        const unsigned short* __restrict__ B2, float* __restrict__ Pp,
        int M, int nslab) {
    __shared__ __align__(16) unsigned short AsH[128*64];   // 16 KB
    __shared__ __align__(16) unsigned short AsL[128*64];   // 16 KB
    __shared__ __align__(16) unsigned short BsH[192*64];   // 24 KB
    __shared__ __align__(16) unsigned short BsL[192*64];   // 24 KB
    int tid = threadIdx.x, lane = tid & 63, wid = tid >> 6;
    int bm = blockIdx.x * 128;
    int zc = blockIdx.y;
    int l15 = lane & 15, l4 = lane >> 4;
    int sw = l15 & 7;
    f32x4 acc2[2][12] = {};
    int kbase = zc * nslab * 64;
    for (int t = 0; t < nslab; ++t) {
        int kp = kbase + t*64;
        #pragma unroll
        for (int i = 0; i < 4; ++i) {
            int c = tid + i*256;
            int row = c >> 3, kb = swz_src8(c);
            GLOAD_LDS16(Gh + (size_t)(bm + row)*4096 + kp + kb, AsH + c*8);
            GLOAD_LDS16(Gl + (size_t)(bm + row)*4096 + kp + kb, AsL + c*8);
        }
        #pragma unroll
        for (int i = 0; i < 6; ++i) {
            int c = tid + i*256;
            int row = c >> 3, kb = swz_src8(c);
            GLOAD_LDS16(B2 + (size_t)row*8192 + kp + kb, BsH + c*8);
            GLOAD_LDS16(B2 + (size_t)row*8192 + 4096 + kp + kb, BsL + c*8);
        }
        __syncthreads();
        #pragma unroll
        for (int kk = 0; kk < 2; ++kk) {
            int cs = ((kk*4 + l4) ^ sw) * 8;
            short8 ah[2], al[2];
            #pragma unroll
            for (int mi = 0; mi < 2; ++mi) {
                int row = wid*32 + mi*16 + l15;
                ah[mi] = *(const short8*)&AsH[row*64 + cs];
                al[mi] = *(const short8*)&AsL[row*64 + cs];
            }
            #pragma unroll
            for (int jn = 0; jn < 12; ++jn) {
                int brow = jn*16 + l15;
                short8 bh = *(const short8*)&BsH[brow*64 + cs];
                short8 bl = *(const short8*)&BsL[brow*64 + cs];
                #pragma unroll
                for (int mi = 0; mi < 2; ++mi) {
                    acc2[mi][jn] = __builtin_amdgcn_mfma_f32_16x16x32_bf16(ah[mi], bh, acc2[mi][jn], 0, 0, 0);
                    acc2[mi][jn] = __builtin_amdgcn_mfma_f32_16x16x32_bf16(ah[mi], bl, acc2[mi][jn], 0, 0, 0);
                    acc2[mi][jn] = __builtin_amdgcn_mfma_f32_16x16x32_bf16(al[mi], bh, acc2[mi][jn], 0, 0, 0);
                }
            }
        }
        __syncthreads();
    }
    #pragma unroll
    for (int jn = 0; jn < 12; ++jn) {
        int col = jn*16 + l15;
        #pragma unroll
        for (int mi = 0; mi < 2; ++mi)
            #pragma unroll
            for (int r = 0; r < 4; ++r) {
                int row = bm + wid*32 + mi*16 + l4*4 + r;
                Pp[((size_t)zc*M + row)*192 + col] = acc2[mi][jn][r];
            }
    }
}

// ======================================================================
// Launch
// ======================================================================
extern "C" void kernel_launch(void* const* d_in, const int* in_sizes, int n_in,
                              void* d_out, int out_size, void* d_ws, size_t ws_size,
                              hipStream_t stream) {
    const float* x  = (const float*)d_in[0];
    const float* w0 = (const float*)d_in[1];
    const float* w1 = (const float*)d_in[2];
    const float* wl = (const float*)d_in[3];
    float* out = (float*)d_out;

    unsigned short* Wsplit = (unsigned short*)(g_scratch + WS_OFF);
    unsigned short* Apack  = (unsigned short*)(g_scratch + AP_OFF);
    unsigned short* Bpack  = (unsigned short*)(g_scratch + BP_OFF);
    unsigned short* A1     = (unsigned short*)(g_scratch + A1_OFF);
    unsigned short* Gh     = (unsigned short*)(g_scratch + GH_OFF);
    unsigned short* Gl     = (unsigned short*)(g_scratch + GL_OFF);
    float* Pp   = g_scratch + PP_OFF;
    float* zbuf = g_scratch + ZB_OFF;
    float* psi2 = g_scratch + PSI2_OFF;

    // zero pad regions (Apack+Bpack+A1 contiguous)
    (void)hipMemsetAsync(g_scratch + AP_OFF, 0, (1013760 + 2027520 + 2359296)*sizeof(float), stream);

    // -------- layer 0 tables (Fin=32, Fout=64) --------
    PsiArgs ps0; APackArgs ap0; LinArgs ln0;
    {
        const int kp[5]   = {64, 128, 192, 256, 320};
        const int kl[5]   = {32, 96, 160, 224, 288};
        const int aoff[5] = {0, 12288, 86016, 270336, 614400};
        const int cumT[6] = {0, 1, 10, 35, 84, 165};
        const int cumE[6] = {0, 2048, 20480, 71680, 172032, 337920};
        ps0.A = Wsplit; ps0.B = g_DKS; ps0.O = Bpack; ps0.fout = 64;
        ap0.X = x; ap0.O = Apack; ap0.bs = 32*455; ap0.fs = 455; ap0.total = 337920;
        ln0.A = Apack; ln0.B = Bpack; ln0.O = A1; ln0.fout = 64;
        for (int l = 0; l < 5; ++l) {
            ps0.boff[l] = aoff[l]; ps0.kp[l] = kp[l];
            ap0.aoff[l] = aoff[l]; ap0.kp[l] = kp[l]; ap0.kl[l] = kl[l];
            ln0.aoff[l] = aoff[l]; ln0.boff[l] = aoff[l]; ln0.kp[l] = kp[l];
            ln0.rs[l] = 1.0f/sqrtf(32.0f*(2*l+1));
        }
        for (int i = 0; i < 6; ++i) { ap0.cum[i] = cumE[i]; ln0.cum[i] = cumT[i]; }
    }
    // -------- layer 1 tables (Fin=64, Fout=128) --------
    PsiArgs ps1; APackArgs ap1; LinArgs ln1;
    {
        const int kp[5]   = {64, 192, 320, 448, 576};
        const int aoff[5] = {0, 12288, 122880, 430080, 1032192};
        const int boff[5] = {0, 24576, 245760, 860160, 2064384};
        const int cumT[6] = {0, 2, 20, 70, 168, 330};
        const int cumE[6] = {0, 4096, 40960, 143360, 344064, 675840};
        ps1.A = Wsplit; ps1.B = g_DKS; ps1.O = Bpack; ps1.fout = 128;
        ap1.X = zbuf; ap1.O = Apack; ap1.bs = 64*192; ap1.fs = 192; ap1.total = 675840;
        ln1.A = Apack; ln1.B = Bpack; ln1.O = A1; ln1.fout = 128;
        for (int l = 0; l < 5; ++l) {
            ps1.boff[l] = boff[l]; ps1.kp[l] = kp[l];
            ap1.aoff[l] = aoff[l]; ap1.kp[l] = kp[l]; ap1.kl[l] = kp[l];
            ln1.aoff[l] = aoff[l]; ln1.boff[l] = boff[l]; ln1.kp[l] = kp[l];
            ln1.rs[l] = 1.0f/sqrtf(64.0f*(2*l+1));
        }
        for (int i = 0; i < 6; ++i) { ap1.cum[i] = cumE[i]; ln1.cum[i] = cumT[i]; }
    }

    // ---- layer 0 ----
    sph_wpack_kernel<<<(2048*192 + 255)/256, 256, 0, stream>>>(w0, Wsplit, 2048*192);
    sph_psi_mfma<<<dim3(2048/64, 3), 256, 0, stream>>>(ps0, 2048);
    sph_apack_kernel<<<(337920 + 255)/256, 256, 0, stream>>>(ap0);
    sph_lin_mfma<<<165, 256, 0, stream>>>(ln0);
    // ---- act 1 (P = 4096) ----
    sph_gemm1_mfma<<<dim3(4096/128, 4096/128), 256, 0, stream>>>(A1, g_B1, g_QW, Gh, Gl, 4096);
    sph_gemm2_mfma<<<dim3(4096/128, 8), 256, 0, stream>>>(Gh, Gl, g_B2T, Pp, 4096, 8);
    sph_reduce_kernel<<<(4096*192 + 255)/256, 256, 0, stream>>>(Pp, zbuf, 4096, 8);
    // ---- layer 1 ----
    sph_wpack_kernel<<<(8192*192 + 255)/256, 256, 0, stream>>>(w1, Wsplit, 8192*192);
    sph_psi_mfma<<<dim3(8192/64, 3), 256, 0, stream>>>(ps1, 8192);
    sph_apack_kernel<<<(675840 + 255)/256, 256, 0, stream>>>(ap1);
    sph_lin_mfma<<<330, 256, 0, stream>>>(ln1);
    // ---- act 2 (P = 8192) ----
    sph_gemm1_mfma<<<dim3(8192/128, 4096/128), 256, 0, stream>>>(A1, g_B1, g_QW, Gh, Gl, 8192);
    sph_gemm2_mfma<<<dim3(8192/128, 8), 256, 0, stream>>>(Gh, Gl, g_B2T, Pp, 8192, 8);
    sph_reduce_kernel<<<(8192*192 + 255)/256, 256, 0, stream>>>(Pp, zbuf, 8192, 8);
    // ---- head ----
    sph_psi2_kernel<<<64, 256, 0, stream>>>(wl, g_YS2, psi2);
    sph_s2_wave<<<8192, 64, 0, stream>>>(zbuf, psi2, out);
}

// Round 10
// 437.862 us; speedup vs baseline: 1.1750x; 1.1750x over previous
//
#include <hip/hip_runtime.h>
#include <cmath>
#include <complex>
#include <cstring>
#include <vector>

#ifndef M_PI
#define M_PI 3.14159265358979323846
#endif

// ======================================================================
// Host-side Wigner-D constant generation (double precision, e3nn conv.)
// Runs once at dlopen (static constructor) — outside graph capture.
// ======================================================================
namespace wig {

using cplx = std::complex<double>;

static void matmul(const double* A, const double* B, double* C, int d) {
    for (int i = 0; i < d; ++i)
        for (int j = 0; j < d; ++j) {
            double s = 0;
            for (int k = 0; k < d; ++k) s += A[i*d+k]*B[k*d+j];
            C[i*d+j] = s;
        }
}

struct Gen { std::vector<double> X0, X1; int d; };

static Gen make_gen(int l) {
    int d = 2*l+1;
    std::vector<cplx> rais(d*d, cplx(0,0)), low(d*d, cplx(0,0));
    for (int i = 0; i+1 < d; ++i) {
        double m = -l + i;
        rais[(i+1)*d + i] = cplx(-std::sqrt(l*(l+1.0) - m*(m+1.0)), 0.0);
    }
    for (int i = 0; i+1 < d; ++i) {
        double m = -l + 1 + i;
        low[i*d + (i+1)] = cplx(std::sqrt(l*(l+1.0) - m*(m-1.0)), 0.0);
    }
    std::vector<cplx> Xc0(d*d, cplx(0,0)), Xc1(d*d, cplx(0,0));
    for (int i = 0; i < d*d; ++i) Xc0[i] = 0.5*(rais[i] + low[i]);
    for (int i = 0; i < d; ++i) Xc1[i*d+i] = cplx(0.0, (double)(-l + i));
    std::vector<cplx> q(d*d, cplx(0,0));
    double is2 = 1.0/std::sqrt(2.0);
    for (int m = -l; m < 0; ++m) {
        q[(l+m)*d + (l-m)] = cplx(is2, 0);
        q[(l+m)*d + (l+m)] = cplx(0, -is2);
    }
    q[l*d + l] = cplx(1,0);
    for (int m = 1; m <= l; ++m) {
        double sgn = (m & 1) ? -1.0 : 1.0;
        q[(l+m)*d + (l+m)] = cplx(sgn*is2, 0);
        q[(l+m)*d + (l-m)] = cplx(0, sgn*is2);
    }
    cplx f;
    switch (l & 3) { case 0: f = cplx(1,0); break; case 1: f = cplx(0,-1); break;
                     case 2: f = cplx(-1,0); break; default: f = cplx(0,1); break; }
    for (auto& v : q) v *= f;
    Gen g; g.d = d; g.X0.assign(d*d, 0.0); g.X1.assign(d*d, 0.0);
    const std::vector<cplx>* Xs[2] = {&Xc0, &Xc1};
    std::vector<double>* Xr[2] = {&g.X0, &g.X1};
    for (int a = 0; a < 2; ++a) {
        std::vector<cplx> t1(d*d, cplx(0,0)), t2(d*d, cplx(0,0));
        for (int i = 0; i < d; ++i)
            for (int k = 0; k < d; ++k) {
                cplx x = (*Xs[a])[i*d+k];
                if (x == cplx(0,0)) continue;
                for (int j = 0; j < d; ++j) t1[i*d+j] += x*q[k*d+j];
            }
        for (int k = 0; k < d; ++k)
            for (int i = 0; i < d; ++i) {
                cplx qc = std::conj(q[k*d+i]);
                if (qc == cplx(0,0)) continue;
                for (int j = 0; j < d; ++j) t2[i*d+j] += qc*t1[k*d+j];
            }
        for (int i = 0; i < d*d; ++i) (*Xr[a])[i] = t2[i].real();
    }
    return g;
}

static std::vector<double> expm_t(const std::vector<double>& A, int d, double t) {
    std::vector<double> M(d*d);
    for (int i = 0; i < d*d; ++i) M[i] = A[i]*t;
    double nrm = 0;
    for (int i = 0; i < d; ++i) {
        double rs = 0;
        for (int j = 0; j < d; ++j) rs += std::fabs(M[i*d+j]);
        if (rs > nrm) nrm = rs;
    }
    int sq = 0;
    while (nrm > 0.5) { nrm *= 0.5; ++sq; }
    double sc = std::ldexp(1.0, -sq);
    for (auto& v : M) v *= sc;
    std::vector<double> R(d*d, 0.0), T(d*d, 0.0), tmp(d*d);
    for (int i = 0; i < d; ++i) { R[i*d+i] = 1.0; T[i*d+i] = 1.0; }
    for (int k = 1; k <= 26; ++k) {
        matmul(T.data(), M.data(), tmp.data(), d);
        double inv = 1.0/(double)k;
        for (int i = 0; i < d*d; ++i) { T[i] = tmp[i]*inv; R[i] += T[i]; }
    }
    for (int s = 0; s < sq; ++s) { matmul(R.data(), R.data(), tmp.data(), d); R = tmp; }
    return R;
}

static std::vector<double> wigD(const Gen& g, double a, double b, double c) {
    auto Ea = expm_t(g.X1, g.d, a);
    auto Eb = expm_t(g.X0, g.d, b);
    auto Ec = expm_t(g.X1, g.d, c);
    std::vector<double> t(g.d*g.d), r(g.d*g.d);
    matmul(Ea.data(), Eb.data(), t.data(), g.d);
    matmul(t.data(), Ec.data(), r.data(), g.d);
    return r;
}

} // namespace wig

// ======================================================================
// bf16 helpers (hi/lo split), host + device
// ======================================================================
static inline unsigned short f2bf_h(float f) {
    unsigned u; std::memcpy(&u, &f, 4);
    unsigned r = (u + 0x7FFFu + ((u >> 16) & 1u)) >> 16;
    return (unsigned short)r;
}
static inline float bf2f_h(unsigned short s) {
    unsigned u = ((unsigned)s) << 16; float f; std::memcpy(&f, &u, 4); return f;
}
__device__ __forceinline__ unsigned short f2bf_d(float f) {
    unsigned u = __float_as_uint(f);
    return (unsigned short)((u + 0x7FFFu + ((u >> 16) & 1u)) >> 16);
}
__device__ __forceinline__ float bf2f_d(unsigned short s) {
    return __uint_as_float(((unsigned)s) << 16);
}

typedef short short8 __attribute__((ext_vector_type(8)));
typedef float f32x4 __attribute__((ext_vector_type(4)));

#define GLOAD_LDS16(g, l) \
    __builtin_amdgcn_global_load_lds( \
        (const __attribute__((address_space(1))) unsigned int*)(g), \
        (__attribute__((address_space(3))) unsigned int*)(l), 16, 0, 0)

// ======================================================================
// Globals: device constants + private scratch (allocated at dlopen)
// ======================================================================
static float*          g_QW   = nullptr;  // [4096]
static float*          g_YS2  = nullptr;  // [24*9]
static unsigned short* g_DKS  = nullptr;  // [192 rows i][576] = [Dh|Dl|Dh] of D_K^T
static unsigned short* g_B1   = nullptr;  // [4096][576]  = [Dh|Dl|Dh] per row (act GEMM1 B)
static unsigned short* g_B2T  = nullptr;  // [192][8192] = [Dh|Dl] columns (act GEMM2 B)
static float*          g_scratch = nullptr;

// scratch layout (float units, all 16B-aligned)
static const size_t WS_OFF   = 0;                       // Wsplit 8192*576 ush = 2359296 fl
static const size_t AP_OFF   = WS_OFF + 2359296;        // lin Apack 2027520 ush = 1013760 fl
static const size_t BP_OFF   = AP_OFF + 1013760;        // lin Bpack 4055040 ush = 2027520 fl
static const size_t A1_OFF   = BP_OFF + 2027520;        // A1 8192*576 ush = 2359296 fl
static const size_t GH_OFF   = A1_OFF + 2359296;        // 8192*4096 ush = 16777216 fl
static const size_t GL_OFF   = GH_OFF + 16777216;
static const size_t PP_OFF   = GL_OFF + 16777216;       // KC*M*192 fl (max 12582912)
static const size_t ZB_OFF   = PP_OFF + 12582912;       // 8192*192 fl
static const size_t PSI2_OFF = ZB_OFF + 1572864;        // 147456 fl
static const size_t TOTAL_F  = PSI2_OFF + 147456;

namespace {
struct InitCtx {
    InitCtx() {
        using namespace wig;
        Gen gens[5];
        for (int l = 0; l <= 4; ++l) gens[l] = make_gen(l);
        const int loff[5] = {0, 1, 10, 35, 84};

        // ---- near-identity SO3 grid / D_K [192 x 165] ----
        double alpha8[8], beta3[3], preg8[8];
        for (int i = 0; i < 8; ++i) alpha8[i] = 2.0*M_PI*i/8.0;
        for (int i = 0; i < 3; ++i) beta3[i] = (i+1)*(M_PI/8.0)/3.0;
        for (int i = 0; i < 8; ++i) preg8[i] = -2.0*M_PI + i*(4.0*M_PI/7.0);
        std::vector<float> hDK((size_t)192*165);
        for (int ia = 0; ia < 8; ++ia)
        for (int ib = 0; ib < 3; ++ib)
        for (int ic = 0; ic < 8; ++ic) {
            int n = ia*24 + ib*8 + ic;
            double a = alpha8[ia], b = beta3[ib], c = preg8[ic] - alpha8[ia];
            for (int l = 0; l <= 4; ++l) {
                int d = 2*l+1;
                auto Dl = wigD(gens[l], a, b, c);
                double s = std::sqrt(2.0*l+1.0);
                for (int e = 0; e < d*d; ++e)
                    hDK[(size_t)n*165 + loff[l] + e] = (float)(s*Dl[e]);
            }
        }

        // ---- full SO3 grid / D_ACT [4096 x 165], QW [4096] ----
        double ag[16], bg[16];
        for (int i = 0; i < 16; ++i) ag[i] = 2.0*M_PI*i/16.0;
        for (int i = 0; i < 16; ++i) bg[i] = (i+0.5)*M_PI/16.0;
        std::vector<std::vector<double>> Ea[5], Eb[5];
        for (int l = 0; l <= 4; ++l) {
            Ea[l].resize(16); Eb[l].resize(16);
            for (int i = 0; i < 16; ++i) {
                Ea[l][i] = expm_t(gens[l].X1, gens[l].d, ag[i]);
                Eb[l][i] = expm_t(gens[l].X0, gens[l].d, bg[i]);
            }
        }
        double qsum = 0;
        for (int ib = 0; ib < 16; ++ib) qsum += std::sin(bg[ib]);
        qsum *= 256.0;
        std::vector<float> hDA((size_t)4096*165), hQW(4096);
        for (int ia = 0; ia < 16; ++ia)
        for (int ib = 0; ib < 16; ++ib) {
            for (int ic = 0; ic < 16; ++ic)
                hQW[ia*256 + ib*16 + ic] = (float)(std::sin(bg[ib]) / qsum);
            for (int l = 0; l <= 4; ++l) {
                int d = gens[l].d;
                std::vector<double> tAB((size_t)d*d), r((size_t)d*d);
                matmul(Ea[l][ia].data(), Eb[l][ib].data(), tAB.data(), d);
                double s = std::sqrt(2.0*l+1.0);
                for (int ic = 0; ic < 16; ++ic) {
                    int n = ia*256 + ib*16 + ic;
                    matmul(tAB.data(), Ea[l][ic].data(), r.data(), d);
                    for (int e = 0; e < d*d; ++e)
                        hDA[(size_t)n*165 + loff[l] + e] = (float)(s*r[e]);
                }
            }
        }

        // ---- S2 grid / Y_S2 [24 x 9] ----
        const int l2off[3] = {0, 1, 4};
        std::vector<float> hY((size_t)24*9);
        for (int ia = 0; ia < 8; ++ia)
        for (int ib = 0; ib < 3; ++ib) {
            int n = ia*3 + ib;
            for (int l = 0; l <= 2; ++l) {
                int d = 2*l+1;
                auto Dl = wigD(gens[l], alpha8[ia], beta3[ib], 0.0);
                double s = std::sqrt(2.0*l+1.0);
                for (int u = 0; u < d; ++u)
                    hY[(size_t)n*9 + l2off[l] + u] = (float)(s*Dl[u*d + l]);
            }
        }

        // ---- D_K^T split for psi MFMA GEMM: [192 rows i][576] = [Dh|Dl|Dh] ----
        std::vector<unsigned short> hDKS((size_t)192*576, 0);
        for (int i = 0; i < 165; ++i)
            for (int k = 0; k < 192; ++k) {
                float f = hDK[(size_t)k*165 + i];
                unsigned short h = f2bf_h(f);
                unsigned short lo = f2bf_h(f - bf2f_h(h));
                hDKS[(size_t)i*576 + k]       = h;
                hDKS[(size_t)i*576 + 192 + k] = lo;
                hDKS[(size_t)i*576 + 384 + k] = h;
            }

        // ---- hi/lo split of D_ACT, padded 165 -> 192 ----
        std::vector<unsigned short> Dh((size_t)4096*192, 0), Dl2((size_t)4096*192, 0);
        for (int n = 0; n < 4096; ++n)
            for (int i = 0; i < 165; ++i) {
                float f = hDA[(size_t)n*165 + i];
                unsigned short h = f2bf_h(f);
                Dh[(size_t)n*192 + i] = h;
                Dl2[(size_t)n*192 + i] = f2bf_h(f - bf2f_h(h));
            }
        std::vector<unsigned short> hB1((size_t)4096*576);
        for (int n = 0; n < 4096; ++n)
            for (int j = 0; j < 192; ++j) {
                hB1[(size_t)n*576 + j]       = Dh[(size_t)n*192 + j];
                hB1[(size_t)n*576 + 192 + j] = Dl2[(size_t)n*192 + j];
                hB1[(size_t)n*576 + 384 + j] = Dh[(size_t)n*192 + j];
            }
        // B2T [192][8192]: [Dh | Dl] (Gh.Dh + Gh.Dl + Gl.Dh handled in-kernel)
        std::vector<unsigned short> hB2T((size_t)192*8192);
        for (int j = 0; j < 192; ++j)
            for (int k = 0; k < 4096; ++k) {
                hB2T[(size_t)j*8192 + k]        = Dh[(size_t)k*192 + j];
                hB2T[(size_t)j*8192 + 4096 + k] = Dl2[(size_t)k*192 + j];
            }

        // ---- upload ----
        (void)hipMalloc((void**)&g_QW,  hQW.size()*sizeof(float));
        (void)hipMalloc((void**)&g_YS2, hY.size()*sizeof(float));
        (void)hipMalloc((void**)&g_DKS, hDKS.size()*sizeof(unsigned short));
        (void)hipMalloc((void**)&g_B1,  hB1.size()*sizeof(unsigned short));
        (void)hipMalloc((void**)&g_B2T, hB2T.size()*sizeof(unsigned short));
        (void)hipMalloc((void**)&g_scratch, TOTAL_F*sizeof(float));
        (void)hipMemcpy(g_QW,  hQW.data(),  hQW.size()*sizeof(float),  hipMemcpyHostToDevice);
        (void)hipMemcpy(g_YS2, hY.data(),   hY.size()*sizeof(float),   hipMemcpyHostToDevice);
        (void)hipMemcpy(g_DKS, hDKS.data(), hDKS.size()*sizeof(unsigned short), hipMemcpyHostToDevice);
        (void)hipMemcpy(g_B1,  hB1.data(),  hB1.size()*sizeof(unsigned short),  hipMemcpyHostToDevice);
        (void)hipMemcpy(g_B2T, hB2T.data(), hB2T.size()*sizeof(unsigned short), hipMemcpyHostToDevice);
    }
};
static InitCtx g_init_ctx;
} // namespace

// ======================================================================
// Arg structs (passed by value)
// ======================================================================
struct PsiArgs {
    const unsigned short* A;   // Wsplit [M][576]
    const unsigned short* B;   // DKsplit [192][576]
    unsigned short* O;         // lin Bpack
    int boff[5], kp[5];
    int fout;
};
struct APackArgs {
    const float* X;
    unsigned short* O;         // lin Apack
    int cum[6];
    int aoff[5], kp[5], kl[5];
    int bs, fs, total;
};
struct LinArgs {
    const unsigned short* A;   // Apack
    const unsigned short* B;   // Bpack
    unsigned short* O;         // A1 [P][576]
    int cum[6];
    int aoff[5], boff[5], kp[5];
    float rs[5];
    int fout;
};

__device__ __constant__ int c_loff[5] = {0, 1, 10, 35, 84};

// Bank-conflict swizzle (T2, both-sides involution with linear global_load_lds):
//  - staging chunk c (16B units): fetch global col16 = (c ^ (c>>3)) & 7
//  - read of (row, col16): LDS col16' = col16 ^ (row & 7)
__device__ __forceinline__ int swz_src8(int c) { return ((c ^ (c >> 3)) & 7) * 8; }

// ======================================================================
// Small kernels
// ======================================================================

// psi2 head: one thread per (x,y); psi2[x,y,i] = sum_k wl[x,y,k]*Y[k,i]/24
__global__ __launch_bounds__(256) void sph_psi2_kernel(
        const float* __restrict__ wl, const float* __restrict__ Y,
        float* __restrict__ psi2) {
    __shared__ float Ys[216];
    int tid = threadIdx.x;
    if (tid < 216) Ys[tid] = Y[tid];
    __syncthreads();
    int o = blockIdx.x*256 + tid;   // 16384 = 128*128
    const float* w = wl + (size_t)o*24;
    float wv[24];
    #pragma unroll
    for (int k = 0; k < 24; k += 4) {
        f32x4 v = *(const f32x4*)&w[k];
        wv[k] = v[0]; wv[k+1] = v[1]; wv[k+2] = v[2]; wv[k+3] = v[3];
    }
    float acc[9] = {};
    #pragma unroll
    for (int k = 0; k < 24; ++k)
        #pragma unroll
        for (int i = 0; i < 9; ++i)
            acc[i] += wv[k] * Ys[k*9 + i];
    float* po = psi2 + (size_t)o*9;
    #pragma unroll
    for (int i = 0; i < 9; ++i) po[i] = acc[i] * (1.0f/24.0f);
}

// s2 head: one wave per (b,y). out[b,y,idx9], K-reduce over x (128) via lanes.
__global__ __launch_bounds__(64) void sph_s2_wave(
        const float* __restrict__ z, const float* __restrict__ psi2,
        float* __restrict__ out) {
    int blk = blockIdx.x;          // 8192 = 64*128
    int b = blk >> 7, y = blk & 127;
    int lane = threadIdx.x;
    float acc[9] = {};
    #pragma unroll
    for (int xi = 0; xi < 2; ++xi) {
        int x = lane + xi*64;
        const float* zr = z + (size_t)(b*128 + x)*192;
        const float* pr = psi2 + (size_t)(x*128 + y)*9;
        float p[9];
        #pragma unroll
        for (int i = 0; i < 9; ++i) p[i] = pr[i];
        acc[0] += p[0] * zr[0];
        #pragma unroll
        for (int u = 0; u < 3; ++u)
            #pragma unroll
            for (int m = 0; m < 3; ++m)
                acc[1+m] += p[1+u] * zr[1 + u*3 + m];
        #pragma unroll
        for (int u = 0; u < 5; ++u)
            #pragma unroll
            for (int m = 0; m < 5; ++m)
                acc[4+m] += p[4+u] * zr[10 + u*5 + m];
    }
    #pragma unroll
    for (int i = 0; i < 9; ++i) {
        float v = acc[i];
        #pragma unroll
        for (int off = 32; off > 0; off >>= 1)
            v += __shfl_down(v, off, 64);
        acc[i] = v;
    }
    if (lane == 0) {
        float* po = out + (size_t)blk*9;
        const float s0 = 0.0883883476483184406f;   // 1/sqrt(128)
        const float s1 = 0.0510310363079828938f;   // 1/sqrt(384)
        const float s2 = 0.0395284707521047416f;   // 1/sqrt(640)
        po[0] = acc[0] * s0;
        po[1] = acc[1] * s1; po[2] = acc[2] * s1; po[3] = acc[3] * s1;
        po[4] = acc[4] * s2; po[5] = acc[5] * s2; po[6] = acc[6] * s2;
        po[7] = acc[7] * s2; po[8] = acc[8] * s2;
    }
}

// w [M][192] fp32 -> Wsplit [M][576] = [Wh|Wh|Wl]
__global__ void sph_wpack_kernel(const float* __restrict__ w, unsigned short* __restrict__ o, int total) {
    int t = blockIdx.x*blockDim.x + threadIdx.x;
    if (t >= total) return;
    int row = t / 192, k = t % 192;
    float v = w[t];
    unsigned short hi = f2bf_d(v);
    unsigned short lo = f2bf_d(v - bf2f_d(hi));
    size_t b = (size_t)row*576 + k;
    o[b] = hi; o[b+192] = hi; o[b+384] = lo;
}

// lin A-pack: X (fp32, block-l layout) -> Apack bf16 [Ah|Ah|Al] per l
__global__ void sph_apack_kernel(APackArgs ar) {
    int t = blockIdx.x*blockDim.x + threadIdx.x;
    if (t >= ar.total) return;
    int l = 0;
    #pragma unroll
    for (int i = 1; i < 5; ++i) if (t >= ar.cum[i]) l = i;
    int e = t - ar.cum[l];
    int d = 2*l + 1;
    int K = ar.kl[l];
    int row = e / K, k = e % K;
    int b = row / d, m = row % d;
    int x = k / d, u = k % d;
    float v = ar.X[(size_t)b*ar.bs + (size_t)x*ar.fs + c_loff[l] + u*d + m];
    unsigned short hi = f2bf_d(v);
    unsigned short lo = f2bf_d(v - bf2f_d(hi));
    int kp = ar.kp[l];
    size_t base = (size_t)ar.aoff[l] + (size_t)row*(3*kp);
    ar.O[base + k] = hi; ar.O[base + kp + k] = hi; ar.O[base + 2*kp + k] = lo;
}

// reduce split-K partials: z[p][j] = sum_{zz<KC} Pp[zz][p][j]
__global__ void sph_reduce_kernel(const float* __restrict__ Pp, float* __restrict__ z, int P, int KC) {
    int o = blockIdx.x*blockDim.x + threadIdx.x;
    if (o >= P*192) return;
    float s = 0.f;
    for (int zz = 0; zz < KC; ++zz) s += Pp[(size_t)zz*P*192 + o];
    z[o] = s;
}

// ======================================================================
// psi MFMA GEMM: P[(x,y),i] = (Wsplit . DKsplit^T)/192, epilogue scatters
// into lin Bpack bf16 [Bh|Bl|Bh]. Tile 64x64, 4 waves (row-split), K=576.
// ======================================================================
__global__ __launch_bounds__(256) void sph_psi_mfma(PsiArgs ar, int M) {
    __shared__ __align__(16) unsigned short As[64*64];
    __shared__ __align__(16) unsigned short Bs[64*64];
    int tid = threadIdx.x, lane = tid & 63, wid = tid >> 6;
    int l15 = lane & 15, l4 = lane >> 4;
    int sw = l15 & 7;
    int bm = blockIdx.x * 64, bn = blockIdx.y * 64;
    f32x4 acc[4] = {};
    for (int k0 = 0; k0 < 576; k0 += 64) {
        #pragma unroll
        for (int i = 0; i < 2; ++i) {
            int c = tid + i*256;
            int row = c >> 3, kb = swz_src8(c);
            GLOAD_LDS16(ar.A + (size_t)(bm + row)*576 + k0 + kb, As + c*8);
            GLOAD_LDS16(ar.B + (size_t)(bn + row)*576 + k0 + kb, Bs + c*8);
        }
        __syncthreads();
        #pragma unroll
        for (int ks = 0; ks < 2; ++ks) {
            int cs = ((ks*4 + l4) ^ sw) * 8;
            short8 av = *(const short8*)&As[(wid*16 + l15)*64 + cs];
            #pragma unroll
            for (int nj = 0; nj < 4; ++nj) {
                short8 bv = *(const short8*)&Bs[(nj*16 + l15)*64 + cs];
                acc[nj] = __builtin_amdgcn_mfma_f32_16x16x32_bf16(av, bv, acc[nj], 0, 0, 0);
            }
        }
        __syncthreads();
    }
    #pragma unroll
    for (int nj = 0; nj < 4; ++nj) {
        int i = bn + nj*16 + l15;
        if (i >= 165) continue;
        int l, st;
        if (i < 1)       { l = 0; st = 0;  }
        else if (i < 10) { l = 1; st = 1;  }
        else if (i < 35) { l = 2; st = 10; }
        else if (i < 84) { l = 3; st = 35; }
        else             { l = 4; st = 84; }
        int d = 2*l + 1;
        int w = i - st;
        int u = w / d, v = w % d;
        int kp = ar.kp[l];
        #pragma unroll
        for (int r = 0; r < 4; ++r) {
            int R = bm + wid*16 + l4*4 + r;
            int x = R / ar.fout, y = R % ar.fout;
            float val = acc[nj][r] * (1.0f/192.0f);
            unsigned short hi = f2bf_d(val);
            unsigned short lo = f2bf_d(val - bf2f_d(hi));
            size_t base = (size_t)ar.boff[l] + (size_t)(y*d + v)*(3*kp) + (x*d + u);
            ar.O[base] = hi; ar.O[base + kp] = lo; ar.O[base + 2*kp] = hi;
        }
    }
}

// ======================================================================
// lin MFMA GEMM: per-l O[(b,m),(y,v)] = A_l . B_l^T, epilogue writes A1
// [P][576] = [Yh|Yh|Yl] with scale 1/sqrt(Fin*d). Tile 64x64, 4 waves.
// ======================================================================
__global__ __launch_bounds__(256) void sph_lin_mfma(LinArgs ar) {
    int bid = blockIdx.x;
    int l = 0;
    #pragma unroll
    for (int i = 1; i < 5; ++i) if (bid >= ar.cum[i]) l = i;
    int t = bid - ar.cum[l];
    int d = 2*l + 1;
    int NB = (ar.fout >> 6) * d;
    int tm = t / NB, tn = t % NB;
    int K3 = 3 * ar.kp[l];
    const unsigned short* Ab = ar.A + ar.aoff[l] + (size_t)tm*64*K3;
    const unsigned short* Bb = ar.B + ar.boff[l] + (size_t)tn*64*K3;
    __shared__ __align__(16) unsigned short As[64*64];
    __shared__ __align__(16) unsigned short Bs[64*64];
    int tid = threadIdx.x, lane = tid & 63, wid = tid >> 6;
    int l15 = lane & 15, l4 = lane >> 4;
    int sw = l15 & 7;
    f32x4 acc[4] = {};
    for (int k0 = 0; k0 < K3; k0 += 64) {
        #pragma unroll
        for (int i = 0; i < 2; ++i) {
            int c = tid + i*256;
            int row = c >> 3, kb = swz_src8(c);
            GLOAD_LDS16(Ab + (size_t)row*K3 + k0 + kb, As + c*8);
            GLOAD_LDS16(Bb + (size_t)row*K3 + k0 + kb, Bs + c*8);
        }
        __syncthreads();
        #pragma unroll
        for (int ks = 0; ks < 2; ++ks) {
            int cs = ((ks*4 + l4) ^ sw) * 8;
            short8 av = *(const short8*)&As[(wid*16 + l15)*64 + cs];
            #pragma unroll
            for (int nj = 0; nj < 4; ++nj) {
                short8 bv = *(const short8*)&Bs[(nj*16 + l15)*64 + cs];
                acc[nj] = __builtin_amdgcn_mfma_f32_16x16x32_bf16(av, bv, acc[nj], 0, 0, 0);
            }
        }
        __syncthreads();
    }
    float rs = ar.rs[l];
    #pragma unroll
    for (int nj = 0; nj < 4; ++nj) {
        int col = tn*64 + nj*16 + l15;
        int y = col / d, v = col % d;
        #pragma unroll
        for (int r = 0; r < 4; ++r) {
            int row = tm*64 + wid*16 + l4*4 + r;
            int b = row / d, m = row % d;
            float val = acc[nj][r] * rs;
            unsigned short hi = f2bf_d(val);
            unsigned short lo = f2bf_d(val - bf2f_d(hi));
            size_t p = (size_t)(b*ar.fout + y)*576 + c_loff[l] + v*d + m;
            ar.O[p] = hi; ar.O[p + 192] = hi; ar.O[p + 384] = lo;
        }
    }
}

// ======================================================================
// MFMA GEMM 1: S = A1[M,576] . B1[4096,576]^T, epilogue g = sqrt2*relu(s)*qw[n],
// writes Gh/Gl bf16 [M][4096]. Tile 128x128, 4 waves (2x2), 16x16x32 bf16.
// Double-buffered LDS: tile t+1's global_load_lds issued BEFORE computing
// tile t (T3 minimum 2-phase) — load latency hides under 16 MFMAs.
// ======================================================================
__global__ __launch_bounds__(256) void sph_gemm1_mfma(
        const unsigned short* __restrict__ A, const unsigned short* __restrict__ B,
        const float* __restrict__ qw,
        unsigned short* __restrict__ Gh, unsigned short* __restrict__ Gl, int M) {
    constexpr int K = 576;
    __shared__ __align__(16) unsigned short As[2][128*64];
    __shared__ __align__(16) unsigned short Bs[2][128*64];
    int tid = threadIdx.x;
    int lane = tid & 63, wid = tid >> 6;
    int wm = wid >> 1, wn = wid & 1;
    int bm = blockIdx.x * 128, bn = blockIdx.y * 128;
    int l15 = lane & 15, l4 = lane >> 4;
    int sw = l15 & 7;
    // prologue: stage tile 0 into buffer 0
    #pragma unroll
    for (int i = 0; i < 4; ++i) {
        int c = tid + i*256;
        int row = c >> 3, kb = swz_src8(c);
        GLOAD_LDS16(A + (size_t)(bm + row)*K + kb, As[0] + c*8);
        GLOAD_LDS16(B + (size_t)(bn + row)*K + kb, Bs[0] + c*8);
    }
    __syncthreads();
    f32x4 acc[4][4] = {};
    for (int t = 0; t < 9; ++t) {
        int cur = t & 1;
        // issue next tile's loads into the other buffer (before compute)
        if (t < 8) {
            int k0 = (t + 1) * 64;
            #pragma unroll
            for (int i = 0; i < 4; ++i) {
                int c = tid + i*256;
                int row = c >> 3, kb = swz_src8(c);
                GLOAD_LDS16(A + (size_t)(bm + row)*K + k0 + kb, As[cur^1] + c*8);
                GLOAD_LDS16(B + (size_t)(bn + row)*K + k0 + kb, Bs[cur^1] + c*8);
            }
        }
        // compute current buffer
        #pragma unroll
        for (int ks = 0; ks < 2; ++ks) {
            int cs = ((ks*4 + l4) ^ sw) * 8;
            short8 av[4], bv[4];
            #pragma unroll
            for (int mi = 0; mi < 4; ++mi)
                av[mi] = *(const short8*)&As[cur][(wm*64 + mi*16 + l15)*64 + cs];
            #pragma unroll
            for (int nj = 0; nj < 4; ++nj)
                bv[nj] = *(const short8*)&Bs[cur][(wn*64 + nj*16 + l15)*64 + cs];
            #pragma unroll
            for (int mi = 0; mi < 4; ++mi)
                #pragma unroll
                for (int nj = 0; nj < 4; ++nj)
                    acc[mi][nj] = __builtin_amdgcn_mfma_f32_16x16x32_bf16(av[mi], bv[nj], acc[mi][nj], 0, 0, 0);
        }
        __syncthreads();
    }
    const float SQ2 = 1.41421356237309515f;
    #pragma unroll
    for (int mi = 0; mi < 4; ++mi) {
        #pragma unroll
        for (int nj = 0; nj < 4; ++nj) {
            int col = bn + wn*64 + nj*16 + l15;
            float q = qw[col] * SQ2;
            #pragma unroll
            for (int r = 0; r < 4; ++r) {
                int row = bm + wm*64 + mi*16 + l4*4 + r;
                float g = fmaxf(acc[mi][nj][r], 0.f) * q;
                unsigned short hi = f2bf_d(g);
                unsigned short lo = f2bf_d(g - bf2f_d(hi));
                size_t idx = (size_t)row*4096 + col;
                Gh[idx] = hi; Gl[idx] = lo;
            }
        }
    }
}

// ======================================================================
// MFMA GEMM 2 (full-N tile): Z[M,192] = Gh.Dh + Gh.Dl + Gl.Dh over phys K=4096,
// split into KC chunks (blockIdx.y). Tile 128 rows x 192 cols, 4 waves
// (wave tile 32x192). Stages Gh/Gl (16KB ea) + Dh/Dl slabs (24KB ea) = 80KB LDS.
// Partials fp32 -> Pp[zc][M][192].
// ======================================================================
__global__ __launch_bounds__(256) void sph_gemm2_mfma(
        const unsigned short* __restrict__ Gh, const unsigned short* __restrict__ Gl,
        const unsigned short* __restrict__ B2, float* __restrict__ Pp,
        int M, int nslab) {
    __shared__ __align__(16) unsigned short AsH[128*64];   // 16 KB
    __shared__ __align__(16) unsigned short AsL[128*64];   // 16 KB
    __shared__ __align__(16) unsigned short BsH[192*64];   // 24 KB
    __shared__ __align__(16) unsigned short BsL[192*64];   // 24 KB
    int tid = threadIdx.x, lane = tid & 63, wid = tid >> 6;
    int bm = blockIdx.x * 128;
    int zc = blockIdx.y;
    int l15 = lane & 15, l4 = lane >> 4;
    int sw = l15 & 7;
    f32x4 acc2[2][12] = {};
    int kbase = zc * nslab * 64;
    for (int t = 0; t < nslab; ++t) {
        int kp = kbase + t*64;
        #pragma unroll
        for (int i = 0; i < 4; ++i) {
            int c = tid + i*256;
            int row = c >> 3, kb = swz_src8(c);
            GLOAD_LDS16(Gh + (size_t)(bm + row)*4096 + kp + kb, AsH + c*8);
            GLOAD_LDS16(Gl + (size_t)(bm + row)*4096 + kp + kb, AsL + c*8);
        }
        #pragma unroll
        for (int i = 0; i < 6; ++i) {
            int c = tid + i*256;
            int row = c >> 3, kb = swz_src8(c);
            GLOAD_LDS16(B2 + (size_t)row*8192 + kp + kb, BsH + c*8);
            GLOAD_LDS16(B2 + (size_t)row*8192 + 4096 + kp + kb, BsL + c*8);
        }
        __syncthreads();
        #pragma unroll
        for (int kk = 0; kk < 2; ++kk) {
            int cs = ((kk*4 + l4) ^ sw) * 8;
            short8 ah[2], al[2];
            #pragma unroll
            for (int mi = 0; mi < 2; ++mi) {
                int row = wid*32 + mi*16 + l15;
                ah[mi] = *(const short8*)&AsH[row*64 + cs];
                al[mi] = *(const short8*)&AsL[row*64 + cs];
            }
            #pragma unroll
            for (int jn = 0; jn < 12; ++jn) {
                int brow = jn*16 + l15;
                short8 bh = *(const short8*)&BsH[brow*64 + cs];
                short8 bl = *(const short8*)&BsL[brow*64 + cs];
                #pragma unroll
                for (int mi = 0; mi < 2; ++mi) {
                    acc2[mi][jn] = __builtin_amdgcn_mfma_f32_16x16x32_bf16(ah[mi], bh, acc2[mi][jn], 0, 0, 0);
                    acc2[mi][jn] = __builtin_amdgcn_mfma_f32_16x16x32_bf16(ah[mi], bl, acc2[mi][jn], 0, 0, 0);
                    acc2[mi][jn] = __builtin_amdgcn_mfma_f32_16x16x32_bf16(al[mi], bh, acc2[mi][jn], 0, 0, 0);
                }
            }
        }
        __syncthreads();
    }
    #pragma unroll
    for (int jn = 0; jn < 12; ++jn) {
        int col = jn*16 + l15;
        #pragma unroll
        for (int mi = 0; mi < 2; ++mi)
            #pragma unroll
            for (int r = 0; r < 4; ++r) {
                int row = bm + wid*32 + mi*16 + l4*4 + r;
                Pp[((size_t)zc*M + row)*192 + col] = acc2[mi][jn][r];
            }
    }
}

// ======================================================================
// Launch
// ======================================================================
extern "C" void kernel_launch(void* const* d_in, const int* in_sizes, int n_in,
                              void* d_out, int out_size, void* d_ws, size_t ws_size,
                              hipStream_t stream) {
    const float* x  = (const float*)d_in[0];
    const float* w0 = (const float*)d_in[1];
    const float* w1 = (const float*)d_in[2];
    const float* wl = (const float*)d_in[3];
    float* out = (float*)d_out;

    unsigned short* Wsplit = (unsigned short*)(g_scratch + WS_OFF);
    unsigned short* Apack  = (unsigned short*)(g_scratch + AP_OFF);
    unsigned short* Bpack  = (unsigned short*)(g_scratch + BP_OFF);
    unsigned short* A1     = (unsigned short*)(g_scratch + A1_OFF);
    unsigned short* Gh     = (unsigned short*)(g_scratch + GH_OFF);
    unsigned short* Gl     = (unsigned short*)(g_scratch + GL_OFF);
    float* Pp   = g_scratch + PP_OFF;
    float* zbuf = g_scratch + ZB_OFF;
    float* psi2 = g_scratch + PSI2_OFF;

    // zero pad regions (Apack+Bpack+A1 contiguous)
    (void)hipMemsetAsync(g_scratch + AP_OFF, 0, (1013760 + 2027520 + 2359296)*sizeof(float), stream);

    // -------- layer 0 tables (Fin=32, Fout=64) --------
    PsiArgs ps0; APackArgs ap0; LinArgs ln0;
    {
        const int kp[5]   = {64, 128, 192, 256, 320};
        const int kl[5]   = {32, 96, 160, 224, 288};
        const int aoff[5] = {0, 12288, 86016, 270336, 614400};
        const int cumT[6] = {0, 1, 10, 35, 84, 165};
        const int cumE[6] = {0, 2048, 20480, 71680, 172032, 337920};
        ps0.A = Wsplit; ps0.B = g_DKS; ps0.O = Bpack; ps0.fout = 64;
        ap0.X = x; ap0.O = Apack; ap0.bs = 32*455; ap0.fs = 455; ap0.total = 337920;
        ln0.A = Apack; ln0.B = Bpack; ln0.O = A1; ln0.fout = 64;
        for (int l = 0; l < 5; ++l) {
            ps0.boff[l] = aoff[l]; ps0.kp[l] = kp[l];
            ap0.aoff[l] = aoff[l]; ap0.kp[l] = kp[l]; ap0.kl[l] = kl[l];
            ln0.aoff[l] = aoff[l]; ln0.boff[l] = aoff[l]; ln0.kp[l] = kp[l];
            ln0.rs[l] = 1.0f/sqrtf(32.0f*(2*l+1));
        }
        for (int i = 0; i < 6; ++i) { ap0.cum[i] = cumE[i]; ln0.cum[i] = cumT[i]; }
    }
    // -------- layer 1 tables (Fin=64, Fout=128) --------
    PsiArgs ps1; APackArgs ap1; LinArgs ln1;
    {
        const int kp[5]   = {64, 192, 320, 448, 576};
        const int aoff[5] = {0, 12288, 122880, 430080, 1032192};
        const int boff[5] = {0, 24576, 245760, 860160, 2064384};
        const int cumT[6] = {0, 2, 20, 70, 168, 330};
        const int cumE[6] = {0, 4096, 40960, 143360, 344064, 675840};
        ps1.A = Wsplit; ps1.B = g_DKS; ps1.O = Bpack; ps1.fout = 128;
        ap1.X = zbuf; ap1.O = Apack; ap1.bs = 64*192; ap1.fs = 192; ap1.total = 675840;
        ln1.A = Apack; ln1.B = Bpack; ln1.O = A1; ln1.fout = 128;
        for (int l = 0; l < 5; ++l) {
            ps1.boff[l] = boff[l]; ps1.kp[l] = kp[l];
            ap1.aoff[l] = aoff[l]; ap1.kp[l] = kp[l]; ap1.kl[l] = kp[l];
            ln1.aoff[l] = aoff[l]; ln1.boff[l] = boff[l]; ln1.kp[l] = kp[l];
            ln1.rs[l] = 1.0f/sqrtf(64.0f*(2*l+1));
        }
        for (int i = 0; i < 6; ++i) { ap1.cum[i] = cumE[i]; ln1.cum[i] = cumT[i]; }
    }

    // ---- layer 0 ----
    sph_wpack_kernel<<<(2048*192 + 255)/256, 256, 0, stream>>>(w0, Wsplit, 2048*192);
    sph_psi_mfma<<<dim3(2048/64, 3), 256, 0, stream>>>(ps0, 2048);
    sph_apack_kernel<<<(337920 + 255)/256, 256, 0, stream>>>(ap0);
    sph_lin_mfma<<<165, 256, 0, stream>>>(ln0);
    // ---- act 1 (P = 4096) ----
    sph_gemm1_mfma<<<dim3(4096/128, 4096/128), 256, 0, stream>>>(A1, g_B1, g_QW, Gh, Gl, 4096);
    sph_gemm2_mfma<<<dim3(4096/128, 8), 256, 0, stream>>>(Gh, Gl, g_B2T, Pp, 4096, 8);
    sph_reduce_kernel<<<(4096*192 + 255)/256, 256, 0, stream>>>(Pp, zbuf, 4096, 8);
    // ---- layer 1 ----
    sph_wpack_kernel<<<(8192*192 + 255)/256, 256, 0, stream>>>(w1, Wsplit, 8192*192);
    sph_psi_mfma<<<dim3(8192/64, 3), 256, 0, stream>>>(ps1, 8192);
    sph_apack_kernel<<<(675840 + 255)/256, 256, 0, stream>>>(ap1);
    sph_lin_mfma<<<330, 256, 0, stream>>>(ln1);
    // ---- act 2 (P = 8192) ----
    sph_gemm1_mfma<<<dim3(8192/128, 4096/128), 256, 0, stream>>>(A1, g_B1, g_QW, Gh, Gl, 8192);
    sph_gemm2_mfma<<<dim3(8192/128, 8), 256, 0, stream>>>(Gh, Gl, g_B2T, Pp, 8192, 8);
    sph_reduce_kernel<<<(8192*192 + 255)/256, 256, 0, stream>>>(Pp, zbuf, 8192, 8);
    // ---- head ----
    sph_psi2_kernel<<<64, 256, 0, stream>>>(wl, g_YS2, psi2);
    sph_s2_wave<<<8192, 64, 0, stream>>>(zbuf, psi2, out);
}